// Round 9
// baseline (205.693 us; speedup 1.0000x reference)
//
#include <hip/hip_runtime.h>
#include <hip/hip_bf16.h>
#include <math.h>

#define NN 8192
#define DD 128
#define BIGF 3.402823466e+38f

typedef __attribute__((ext_vector_type(8))) short short8;
typedef __attribute__((ext_vector_type(4))) float f32x4;

static __device__ __forceinline__ unsigned short bfc(float f) {
    return __bfloat16_as_ushort(__float2bfloat16(f));
}

// ---------------- prep: fp32 -> bf16 + exact fp32 row norms + ws init ----------------
__global__ __launch_bounds__(256) void prep_kernel(const float* __restrict__ A,
                                                   const float* __restrict__ B,
                                                   __hip_bfloat16* __restrict__ Abf,
                                                   __hip_bfloat16* __restrict__ Bbf,
                                                   float* __restrict__ na,
                                                   float* __restrict__ nb,
                                                   unsigned int* __restrict__ minbuf,
                                                   float* __restrict__ partial,
                                                   unsigned int* __restrict__ done) {
    if (blockIdx.y == 0 && blockIdx.x < 64) {
        minbuf[blockIdx.x * 256 + threadIdx.x] = 0xFFFFFFFFu;  // 16384 u32 row+col mins
        if (blockIdx.x == 0 && threadIdx.x < 64) partial[threadIdx.x] = 0.f;
        if (blockIdx.x == 0 && threadIdx.x == 64) *done = 0u;
    }
    const float* x = blockIdx.y ? B : A;
    __hip_bfloat16* xb = blockIdx.y ? Bbf : Abf;
    float* norm = blockIdx.y ? nb : na;
    const int sub = threadIdx.x >> 5;
    const int ch  = threadIdx.x & 31;
    const int row = blockIdx.x * 8 + sub;
    const float4 v = *(const float4*)(x + (size_t)row * DD + ch * 4);
    float s = v.x * v.x + v.y * v.y + v.z * v.z + v.w * v.w;
    uint2 pk;
    pk.x = ((unsigned)bfc(v.y) << 16) | bfc(v.x);
    pk.y = ((unsigned)bfc(v.w) << 16) | bfc(v.z);
    *(uint2*)(xb + (size_t)row * DD + ch * 4) = pk;
#pragma unroll
    for (int off = 16; off >= 1; off >>= 1) s += __shfl_xor(s, off, 64);
    if (ch == 0) norm[row] = s;
}

// ---------------- fused MFMA distance pass, double-buffered LDS ----------------
// loss = 1 - 1/8192 + T/(N*M) - (P_r + P_c)/16384 (hinge never clips since d>=pos).
// 128x128 tile, 4 waves (2x2), each 64x64 = 4x4 frags of 16x16x32 bf16.
// K=128 in 4 phases of 32; LDS = 2 bufs x (A 8KB + B 8KB) = 32 KB.
// Per iter: ds_read(p) -> ds_write(p+1, from regs) -> global_load(p+2 -> regs)
//           -> ONE barrier -> MFMA(p).  Loads fly one full iteration early.
// Row layout: 64 B/row, chunk j stored at ((j ^ ((r>>1)&3))<<4): both ds_read
// (16 rows x same 16B col) and ds_write land 2 lanes/bank = conflict-free.
// Finalize is folded in: last block (done-counter) reduces mins+partials.
__global__ __launch_bounds__(256, 2) void dist_fused(
    const __hip_bfloat16* __restrict__ Ab, const __hip_bfloat16* __restrict__ Bb,
    const float* __restrict__ na, const float* __restrict__ nb,
    unsigned int* __restrict__ rowmin, unsigned int* __restrict__ colmin,
    float* __restrict__ partial, unsigned int* __restrict__ done,
    float* __restrict__ out) {
    __shared__ char lds[32768];
    const int tid = threadIdx.x;
    const int l = tid & 63, wid = tid >> 6;
    const int wr = wid >> 1, wc = wid & 1;
    const int g = l >> 4, c = l & 15;
    const int rowBase = blockIdx.y * 128, colBase = blockIdx.x * 128;
    const int row0 = rowBase + wr * 64, col0 = colBase + wc * 64;

    // staging map: thread t -> row rs = t>>1, chunks jb, jb+1 (jb = (t&1)*2)
    const int rs = tid >> 1, jb = (tid & 1) << 1;
    const char* aSrc = (const char*)Ab + (size_t)(rowBase + rs) * 256 + jb * 16;
    const char* bSrc = (const char*)Bb + (size_t)(colBase + rs) * 256 + jb * 16;
    const int swz = (rs >> 1) & 3;
    const int dst0 = rs * 64 + ((jb ^ swz) << 4);
    const int dst1 = rs * 64 + (((jb + 1) ^ swz) << 4);

    short8 rgA[2][2], rgB[2][2];   // phase x staged in slot x&1 (static indices only)
#define LOADP(x) do {                                                   \
        rgA[(x) & 1][0] = *(const short8*)(aSrc + (x) * 64);            \
        rgA[(x) & 1][1] = *(const short8*)(aSrc + (x) * 64 + 16);       \
        rgB[(x) & 1][0] = *(const short8*)(bSrc + (x) * 64);            \
        rgB[(x) & 1][1] = *(const short8*)(bSrc + (x) * 64 + 16);       \
    } while (0)
#define WRITEP(x) do { const int s_ = ((x) & 1) * 16384;                \
        *(short8*)(lds + s_ + dst0) = rgA[(x) & 1][0];                  \
        *(short8*)(lds + s_ + dst1) = rgA[(x) & 1][1];                  \
        *(short8*)(lds + s_ + 8192 + dst0) = rgB[(x) & 1][0];           \
        *(short8*)(lds + s_ + 8192 + dst1) = rgB[(x) & 1][1];           \
    } while (0)

    f32x4 acc[4][4];
#pragma unroll
    for (int mi = 0; mi < 4; ++mi)
#pragma unroll
        for (int ni = 0; ni < 4; ++ni) acc[mi][ni] = (f32x4)0.f;

    LOADP(0);
    WRITEP(0);
    LOADP(1);
    __syncthreads();

#pragma unroll
    for (int p = 0; p < 4; ++p) {
        short8 af[4], bf[4];
        const int sb = (p & 1) * 16384;
#pragma unroll
        for (int mi = 0; mi < 4; ++mi) {
            int r = wr * 64 + mi * 16 + c;
            af[mi] = *(const short8*)(lds + sb + r * 64 + ((g ^ ((r >> 1) & 3)) << 4));
            int r2 = wc * 64 + mi * 16 + c;
            bf[mi] = *(const short8*)(lds + sb + 8192 + r2 * 64 + ((g ^ ((r2 >> 1) & 3)) << 4));
        }
        if (p == 0) { WRITEP(1); LOADP(2); }
        else if (p == 1) { WRITEP(2); LOADP(3); }
        else if (p == 2) { WRITEP(3); }
        if (p < 3) __syncthreads();
#pragma unroll
        for (int mi = 0; mi < 4; ++mi)
#pragma unroll
            for (int ni = 0; ni < 4; ++ni)
                acc[mi][ni] = __builtin_amdgcn_mfma_f32_16x16x32_bf16(
                    af[mi], bf[ni], acc[mi][ni], 0, 0, 0);
    }
#undef LOADP
#undef WRITEP

    // out_row = row0 + mi*16 + g*4 + reg ; out_col = col0 + ni*16 + c
    float nbc[4];
#pragma unroll
    for (int ni = 0; ni < 4; ++ni) nbc[ni] = nb[col0 + ni * 16 + c];

    float colm[4] = {BIGF, BIGF, BIGF, BIGF};
    f32x4 tot4 = (f32x4)0.f;
#pragma unroll
    for (int mi = 0; mi < 4; ++mi) {
        const f32x4 na4 = *(const f32x4*)(na + row0 + mi * 16 + g * 4);
        float rowm[4] = {BIGF, BIGF, BIGF, BIGF};
#pragma unroll
        for (int ni = 0; ni < 4; ++ni) {
            f32x4 a = acc[mi][ni];
#pragma unroll
            for (int reg = 0; reg < 4; ++reg) {
                float d2 = fmaf(-2.0f, a[reg], na4[reg] + nbc[ni]);
                float d = __builtin_amdgcn_sqrtf(fmaxf(d2, 0.f));
                tot4[reg] += d;
                rowm[reg] = fminf(rowm[reg], d);
                colm[ni] = fminf(colm[ni], d);
            }
        }
#pragma unroll
        for (int reg = 0; reg < 4; ++reg) {
            float m = rowm[reg];
            m = fminf(m, __shfl_xor(m, 1, 64));
            m = fminf(m, __shfl_xor(m, 2, 64));
            m = fminf(m, __shfl_xor(m, 4, 64));
            m = fminf(m, __shfl_xor(m, 8, 64));
            rowm[reg] = m;
        }
        if (c == 0) {
#pragma unroll
            for (int reg = 0; reg < 4; ++reg)
                atomicMin(&rowmin[row0 + mi * 16 + g * 4 + reg],
                          __float_as_uint(rowm[reg]));
        }
    }
#pragma unroll
    for (int ni = 0; ni < 4; ++ni) {
        float m = colm[ni];
        m = fminf(m, __shfl_xor(m, 16, 64));
        m = fminf(m, __shfl_xor(m, 32, 64));
        if (g == 0) atomicMin(&colmin[col0 + ni * 16 + c], __float_as_uint(m));
    }
    float tot = (tot4[0] + tot4[1]) + (tot4[2] + tot4[3]);
#pragma unroll
    for (int off = 32; off >= 1; off >>= 1) tot += __shfl_xor(tot, off, 64);
    if (l == 0) atomicAdd(&partial[blockIdx.y], tot);

    // ---- folded finalize: last finishing block reduces everything ----
    __syncthreads();   // all waves' atomics drained (waitcnt before barrier)
    unsigned* flag = (unsigned*)lds;
    if (tid == 0) {
        __threadfence();                       // release our atomics
        unsigned prev = atomicAdd(done, 1u);
        *flag = (prev == 64u * 64u - 1u) ? 1u : 0u;
    }
    __syncthreads();
    if (*flag) {
        __threadfence();                       // acquire side
        float msum = 0.f;
        for (int i = tid; i < 16384; i += 256) {
            unsigned u = __hip_atomic_load(&rowmin[i], __ATOMIC_RELAXED,
                                           __HIP_MEMORY_SCOPE_AGENT);
            msum += __uint_as_float(u);        // rowmin..colmin contiguous
        }
        float cacc = msum * (-1.0f / 16384.0f);
        if (tid < 64)
            cacc += __hip_atomic_load(&partial[tid], __ATOMIC_RELAXED,
                                      __HIP_MEMORY_SCOPE_AGENT) *
                    (1.0f / 67108864.0f);
#pragma unroll
        for (int off = 32; off >= 1; off >>= 1) cacc += __shfl_xor(cacc, off, 64);
        float* red = (float*)(lds + 64);
        if (l == 0) red[wid] = cacc;
        __syncthreads();
        if (tid == 0)
            out[0] = (red[0] + red[1] + red[2] + red[3]) + 1.0f - 1.0f / 8192.0f;
    }
}

extern "C" void kernel_launch(void* const* d_in, const int* in_sizes, int n_in,
                              void* d_out, int out_size, void* d_ws, size_t ws_size,
                              hipStream_t stream) {
    const float* A = (const float*)d_in[0];
    const float* B = (const float*)d_in[1];
    char* ws = (char*)d_ws;

    const size_t MB = 1024 * 1024;
    __hip_bfloat16* Abf = (__hip_bfloat16*)(ws);                 // 2 MB
    __hip_bfloat16* Bbf = (__hip_bfloat16*)(ws + 2 * MB);        // 2 MB
    float* na            = (float*)(ws + 4 * MB);                // 32 KB
    float* nb            = (float*)(ws + 4 * MB + 32768);        // 32 KB
    unsigned int* rowmin = (unsigned int*)(ws + 4 * MB + 65536); // 32 KB
    unsigned int* colmin = (unsigned int*)(ws + 4 * MB + 98304); // 32 KB (contig after rowmin)
    float* partial       = (float*)(ws + 4 * MB + 131072);       // 256 B
    unsigned int* done   = (unsigned int*)(ws + 4 * MB + 131072 + 256);

    dim3 pgrid(NN / 8, 2);
    prep_kernel<<<pgrid, 256, 0, stream>>>(A, B, Abf, Bbf, na, nb, rowmin, partial, done);

    dim3 grid(NN / 128, NN / 128);
    dist_fused<<<grid, 256, 0, stream>>>(Abf, Bbf, na, nb, rowmin, colmin, partial,
                                         done, (float*)d_out);
}

// Round 10
// 67.325 us; speedup vs baseline: 3.0552x; 3.0552x over previous
//
#include <hip/hip_runtime.h>
#include <hip/hip_bf16.h>
#include <math.h>

#define NN 8192
#define DD 128
#define BIGF 3.402823466e+38f

typedef __attribute__((ext_vector_type(8))) short short8;
typedef __attribute__((ext_vector_type(4))) float f32x4;

static __device__ __forceinline__ unsigned short bfc(float f) {
    return __bfloat16_as_ushort(__float2bfloat16(f));
}

// ---------------- prep: fp32 -> bf16 + exact fp32 row norms ----------------
// No workspace init needed: all partial buffers are fully overwritten downstream.
__global__ __launch_bounds__(256) void prep_kernel(const float* __restrict__ A,
                                                   const float* __restrict__ B,
                                                   __hip_bfloat16* __restrict__ Abf,
                                                   __hip_bfloat16* __restrict__ Bbf,
                                                   float* __restrict__ na,
                                                   float* __restrict__ nb) {
    const float* x = blockIdx.y ? B : A;
    __hip_bfloat16* xb = blockIdx.y ? Bbf : Abf;
    float* norm = blockIdx.y ? nb : na;
    const int sub = threadIdx.x >> 5;
    const int ch  = threadIdx.x & 31;
    const int row = blockIdx.x * 8 + sub;
    const float4 v = *(const float4*)(x + (size_t)row * DD + ch * 4);
    float s = v.x * v.x + v.y * v.y + v.z * v.z + v.w * v.w;
    uint2 pk;
    pk.x = ((unsigned)bfc(v.y) << 16) | bfc(v.x);
    pk.y = ((unsigned)bfc(v.w) << 16) | bfc(v.z);
    *(uint2*)(xb + (size_t)row * DD + ch * 4) = pk;
#pragma unroll
    for (int off = 16; off >= 1; off >>= 1) s += __shfl_xor(s, off, 64);
    if (ch == 0) norm[row] = s;
}

// ---------------- fused MFMA distance pass, ZERO ATOMICS ----------------
// loss = 1 - 1/8192 + T/(N*M) - (P_r + P_c)/16384 (hinge never clips: d >= pos).
// Mins tracked on d^2 (sqrt is monotone -> min commutes with sqrt).
// 128x128 tile per block, 4 waves (2x2), each 64x64 = 4x4 frags of 16x16x32.
// K staged in two 64-wide phases -> 32 KB LDS (R6's proven structure, verbatim).
// Epilogue: cross-wave combine in LDS, then PLAIN coalesced stores to disjoint
// per-block partial buffers (rowpart[ct][row], colpart[rt][col], totpart[blk]).
// R4-R9 lesson: the constant ~21 MB WRITE_SIZE was ~1M device-scope atomics
// hammering 64 KB (cross-XCD coherence point serialization) - not spill.
__global__ __launch_bounds__(256, 4) void dist_fused(
    const __hip_bfloat16* __restrict__ Ab, const __hip_bfloat16* __restrict__ Bb,
    const float* __restrict__ na, const float* __restrict__ nb,
    float* __restrict__ rowpart, float* __restrict__ colpart,
    float* __restrict__ totpart) {
    __shared__ char lds[32768];
    char* ldsA = lds;
    char* ldsB = lds + 16384;
    const int tid = threadIdx.x;
    const int rowBase = blockIdx.y * 128;
    const int colBase = blockIdx.x * 128;

    const unsigned short* aG = (const unsigned short*)Ab + (size_t)rowBase * DD;
    const unsigned short* bG = (const unsigned short*)Bb + (size_t)colBase * DD;

    const int l = tid & 63, wid = tid >> 6;
    const int wr = wid >> 1, wc = wid & 1;   // wave 64x64 sub-tile
    const int g = l >> 4, c = l & 15;

    f32x4 acc[4][4];
#pragma unroll
    for (int mi = 0; mi < 4; ++mi)
#pragma unroll
        for (int ni = 0; ni < 4; ++ni) acc[mi][ni] = (f32x4)0.f;

#pragma unroll
    for (int p = 0; p < 2; ++p) {
        if (p) __syncthreads();   // previous compute done before overwrite
        // stage 128 rows x 64 bf16 (128 B/row) of A and B, XOR-swizzled
#pragma unroll
        for (int it = 0; it < 4; ++it) {
            int idx = tid + 256 * it;   // 0..1023
            int r = idx >> 3;           // row 0..127
            int c16 = idx & 7;          // 16B chunk in row
            int dst = r * 128 + ((c16 * 16) ^ ((r & 7) << 4));
            *(short8*)(ldsA + dst) = *(const short8*)(aG + r * DD + p * 64 + c16 * 8);
            *(short8*)(ldsB + dst) = *(const short8*)(bG + r * DD + p * 64 + c16 * 8);
        }
        __syncthreads();
#pragma unroll
        for (int kk = 0; kk < 2; ++kk) {
            short8 af[4], bf[4];
            const int kbyte = kk * 64 + g * 16;
#pragma unroll
            for (int mi = 0; mi < 4; ++mi) {
                int r = wr * 64 + mi * 16 + c;
                af[mi] = *(const short8*)(ldsA + r * 128 + (kbyte ^ ((r & 7) << 4)));
                int r2 = wc * 64 + mi * 16 + c;
                bf[mi] = *(const short8*)(ldsB + r2 * 128 + (kbyte ^ ((r2 & 7) << 4)));
            }
#pragma unroll
            for (int mi = 0; mi < 4; ++mi)
#pragma unroll
                for (int ni = 0; ni < 4; ++ni)
                    acc[mi][ni] = __builtin_amdgcn_mfma_f32_16x16x32_bf16(
                        af[mi], bf[ni], acc[mi][ni], 0, 0, 0);
        }
    }

    // out_row = row0 + mi*16 + g*4 + reg ; out_col = col0 + ni*16 + c
    const int row0 = rowBase + wr * 64;
    const int col0 = colBase + wc * 64;

    float nbc[4];
#pragma unroll
    for (int ni = 0; ni < 4; ++ni) nbc[ni] = nb[col0 + ni * 16 + c];

    // epilogue LDS buffers overlay ldsA (safe after the barrier below)
    float* rmbuf = (float*)lds;            // [2][128] : [wc][row_in_block]
    float* cmbuf = (float*)(lds + 1024);   // [2][128] : [wr][col_in_block]
    float* tbuf  = (float*)(lds + 2048);   // [4]
    __syncthreads();   // all waves done with final-phase ds_reads

    float colm2[4] = {BIGF, BIGF, BIGF, BIGF};
    f32x4 tot4 = (f32x4)0.f;
#pragma unroll
    for (int mi = 0; mi < 4; ++mi) {
        const f32x4 na4 = *(const f32x4*)(na + row0 + mi * 16 + g * 4);
        float rowm2[4] = {BIGF, BIGF, BIGF, BIGF};
#pragma unroll
        for (int ni = 0; ni < 4; ++ni) {
            f32x4 a = acc[mi][ni];
#pragma unroll
            for (int reg = 0; reg < 4; ++reg) {
                float d2 = fmaf(-2.0f, a[reg], na4[reg] + nbc[ni]);
                rowm2[reg] = fminf(rowm2[reg], d2);
                colm2[ni] = fminf(colm2[ni], d2);
                tot4[reg] += __builtin_amdgcn_sqrtf(fmaxf(d2, 0.f));
            }
        }
        // row d^2 mins: reduce across the 16 c-lanes
#pragma unroll
        for (int reg = 0; reg < 4; ++reg) {
            float m = rowm2[reg];
            m = fminf(m, __shfl_xor(m, 1, 64));
            m = fminf(m, __shfl_xor(m, 2, 64));
            m = fminf(m, __shfl_xor(m, 4, 64));
            m = fminf(m, __shfl_xor(m, 8, 64));
            if (c == 0) rmbuf[wc * 128 + wr * 64 + mi * 16 + g * 4 + reg] = m;
        }
    }
    // col d^2 mins: reduce across the 4 g-groups
#pragma unroll
    for (int ni = 0; ni < 4; ++ni) {
        float m = colm2[ni];
        m = fminf(m, __shfl_xor(m, 16, 64));
        m = fminf(m, __shfl_xor(m, 32, 64));
        if (g == 0) cmbuf[wr * 128 + wc * 64 + ni * 16 + c] = m;
    }
    // grand total: wave reduce
    float tot = (tot4[0] + tot4[1]) + (tot4[2] + tot4[3]);
#pragma unroll
    for (int off = 32; off >= 1; off >>= 1) tot += __shfl_xor(tot, off, 64);
    if (l == 0) tbuf[wid] = tot;
    __syncthreads();

    // plain disjoint stores - no atomics anywhere
    if (tid < 128) {
        rowpart[(size_t)blockIdx.x * NN + rowBase + tid] =
            fminf(rmbuf[tid], rmbuf[128 + tid]);
    } else if (tid < 256) {
        int j = tid - 128;
        colpart[(size_t)blockIdx.y * NN + colBase + j] =
            fminf(cmbuf[j], cmbuf[128 + j]);
    }
    if (tid == 0)
        totpart[blockIdx.y * 64 + blockIdx.x] = tbuf[0] + tbuf[1] + tbuf[2] + tbuf[3];
}

// ---------------- fin1: 64-way partial reduce (64 blocks x 256 threads) ----------------
__global__ __launch_bounds__(256) void fin1_kernel(const float* __restrict__ rowpart,
                                                   const float* __restrict__ colpart,
                                                   const float* __restrict__ totpart,
                                                   float* __restrict__ finpart) {
    const int idx = blockIdx.x * 256 + threadIdx.x;   // 0..16383
    const int j = (idx < NN) ? idx : idx - NN;
    const float* p = (idx < NN) ? rowpart : colpart;
    float m = BIGF;
#pragma unroll 8
    for (int k = 0; k < 64; ++k) m = fminf(m, p[(size_t)k * NN + j]);
    float contrib = -__builtin_amdgcn_sqrtf(fmaxf(m, 0.f)) * (1.0f / 16384.0f);
    if (blockIdx.x < 16)
        contrib += totpart[blockIdx.x * 256 + threadIdx.x] * (1.0f / 67108864.0f);
#pragma unroll
    for (int off = 32; off >= 1; off >>= 1) contrib += __shfl_xor(contrib, off, 64);
    __shared__ float red[4];
    if ((threadIdx.x & 63) == 0) red[threadIdx.x >> 6] = contrib;
    __syncthreads();
    if (threadIdx.x == 0)
        finpart[blockIdx.x] = red[0] + red[1] + red[2] + red[3];
}

// ---------------- fin2: final scalar ----------------
__global__ __launch_bounds__(64) void fin2_kernel(const float* __restrict__ finpart,
                                                  float* __restrict__ out) {
    float s = finpart[threadIdx.x];
#pragma unroll
    for (int off = 32; off >= 1; off >>= 1) s += __shfl_xor(s, off, 64);
    if (threadIdx.x == 0) out[0] = s + 1.0f - 1.0f / 8192.0f;
}

extern "C" void kernel_launch(void* const* d_in, const int* in_sizes, int n_in,
                              void* d_out, int out_size, void* d_ws, size_t ws_size,
                              hipStream_t stream) {
    const float* A = (const float*)d_in[0];
    const float* B = (const float*)d_in[1];
    char* ws = (char*)d_ws;

    const size_t MB = 1024 * 1024;
    __hip_bfloat16* Abf = (__hip_bfloat16*)(ws);                  // 2 MB
    __hip_bfloat16* Bbf = (__hip_bfloat16*)(ws + 2 * MB);         // 2 MB
    float* na      = (float*)(ws + 4 * MB);                       // 32 KB
    float* nb      = (float*)(ws + 4 * MB + 32768);               // 32 KB
    float* rowpart = (float*)(ws + 4 * MB + 65536);               // 2 MB  [ct][8192]
    float* colpart = (float*)(ws + 6 * MB + 65536);               // 2 MB  [rt][8192]
    float* totpart = (float*)(ws + 8 * MB + 65536);               // 16 KB [rt*64+ct]
    float* finpart = (float*)(ws + 8 * MB + 65536 + 16384);       // 256 B

    dim3 pgrid(NN / 8, 2);
    prep_kernel<<<pgrid, 256, 0, stream>>>(A, B, Abf, Bbf, na, nb);

    dim3 grid(NN / 128, NN / 128);
    dist_fused<<<grid, 256, 0, stream>>>(Abf, Bbf, na, nb, rowpart, colpart, totpart);

    fin1_kernel<<<64, 256, 0, stream>>>(rowpart, colpart, totpart, finpart);
    fin2_kernel<<<1, 64, 0, stream>>>(finpart, (float*)d_out);
}

// Round 11
// 66.723 us; speedup vs baseline: 3.0828x; 1.0090x over previous
//
#include <hip/hip_runtime.h>
#include <hip/hip_bf16.h>
#include <math.h>

#define NN 8192
#define DD 128
#define BIGF 3.402823466e+38f

typedef __attribute__((ext_vector_type(8))) short short8;
typedef __attribute__((ext_vector_type(4))) float f32x4;

static __device__ __forceinline__ unsigned short bfc(float f) {
    return __bfloat16_as_ushort(__float2bfloat16(f));
}

// ---------------- prep: fp32 -> bf16 + exact fp32 row norms + done init ----------------
__global__ __launch_bounds__(256) void prep_kernel(const float* __restrict__ A,
                                                   const float* __restrict__ B,
                                                   __hip_bfloat16* __restrict__ Abf,
                                                   __hip_bfloat16* __restrict__ Bbf,
                                                   float* __restrict__ na,
                                                   float* __restrict__ nb,
                                                   unsigned int* __restrict__ done) {
    if (blockIdx.y == 0 && blockIdx.x == 0 && threadIdx.x == 0) *done = 0u;
    const float* x = blockIdx.y ? B : A;
    __hip_bfloat16* xb = blockIdx.y ? Bbf : Abf;
    float* norm = blockIdx.y ? nb : na;
    const int sub = threadIdx.x >> 5;
    const int ch  = threadIdx.x & 31;
    const int row = blockIdx.x * 8 + sub;
    const float4 v = *(const float4*)(x + (size_t)row * DD + ch * 4);
    float s = v.x * v.x + v.y * v.y + v.z * v.z + v.w * v.w;
    uint2 pk;
    pk.x = ((unsigned)bfc(v.y) << 16) | bfc(v.x);
    pk.y = ((unsigned)bfc(v.w) << 16) | bfc(v.z);
    *(uint2*)(xb + (size_t)row * DD + ch * 4) = pk;
#pragma unroll
    for (int off = 16; off >= 1; off >>= 1) s += __shfl_xor(s, off, 64);
    if (ch == 0) norm[row] = s;
}

// ---------------- fused MFMA distance pass, zero atomics, XCD-swizzled ----------------
// loss = 1 - 1/8192 + T/(N*M) - (P_r + P_c)/16384 (hinge never clips: d >= pos).
// Mins tracked on d^2 (sqrt monotone). 128x128 tile, 4 waves (2x2), 64x64/wave.
// K in two 64-wide phases -> 32 KB tile LDS + 2.1 KB epilogue buffers (no overlay
// -> one barrier fewer). Block->tile mapping bijectively swizzled so each XCD
// works on 8 contiguous row-panels x all col-panels: L2 footprint 256KB A + 2MB B
// < 4MB per-XCD L2 (R10 counters: FETCH 10.7MB = 2.7x refetch from round-robin).
__global__ __launch_bounds__(256, 4) void dist_fused(
    const __hip_bfloat16* __restrict__ Ab, const __hip_bfloat16* __restrict__ Bb,
    const float* __restrict__ na, const float* __restrict__ nb,
    float* __restrict__ rowpart, float* __restrict__ colpart,
    float* __restrict__ totpart) {
    __shared__ char lds[32768];
    __shared__ float rmbuf[2][128];   // [wc][row_in_block]
    __shared__ float cmbuf[2][128];   // [wr][col_in_block]
    __shared__ float tbuf[4];
    char* ldsA = lds;
    char* ldsB = lds + 16384;
    const int tid = threadIdx.x;

    // bijective XCD swizzle (4096 blocks, 8 XCDs, 4096 % 8 == 0)
    const int lin = blockIdx.y * 64 + blockIdx.x;
    const int swz = (lin & 7) * 512 + (lin >> 3);
    const int bx = swz & 63, by = swz >> 6;
    const int rowBase = by * 128;
    const int colBase = bx * 128;

    const unsigned short* aG = (const unsigned short*)Ab + (size_t)rowBase * DD;
    const unsigned short* bG = (const unsigned short*)Bb + (size_t)colBase * DD;

    const int l = tid & 63, wid = tid >> 6;
    const int wr = wid >> 1, wc = wid & 1;   // wave 64x64 sub-tile
    const int g = l >> 4, c = l & 15;

    f32x4 acc[4][4];
#pragma unroll
    for (int mi = 0; mi < 4; ++mi)
#pragma unroll
        for (int ni = 0; ni < 4; ++ni) acc[mi][ni] = (f32x4)0.f;

#pragma unroll
    for (int p = 0; p < 2; ++p) {
        if (p) __syncthreads();   // previous compute done before overwrite
        // stage 128 rows x 64 bf16 (128 B/row) of A and B, XOR-swizzled
#pragma unroll
        for (int it = 0; it < 4; ++it) {
            int idx = tid + 256 * it;   // 0..1023
            int r = idx >> 3;           // row 0..127
            int c16 = idx & 7;          // 16B chunk in row
            int dst = r * 128 + ((c16 * 16) ^ ((r & 7) << 4));
            *(short8*)(ldsA + dst) = *(const short8*)(aG + r * DD + p * 64 + c16 * 8);
            *(short8*)(ldsB + dst) = *(const short8*)(bG + r * DD + p * 64 + c16 * 8);
        }
        __syncthreads();
#pragma unroll
        for (int kk = 0; kk < 2; ++kk) {
            short8 af[4], bf[4];
            const int kbyte = kk * 64 + g * 16;
#pragma unroll
            for (int mi = 0; mi < 4; ++mi) {
                int r = wr * 64 + mi * 16 + c;
                af[mi] = *(const short8*)(ldsA + r * 128 + (kbyte ^ ((r & 7) << 4)));
                int r2 = wc * 64 + mi * 16 + c;
                bf[mi] = *(const short8*)(ldsB + r2 * 128 + (kbyte ^ ((r2 & 7) << 4)));
            }
#pragma unroll
            for (int mi = 0; mi < 4; ++mi)
#pragma unroll
                for (int ni = 0; ni < 4; ++ni)
                    acc[mi][ni] = __builtin_amdgcn_mfma_f32_16x16x32_bf16(
                        af[mi], bf[ni], acc[mi][ni], 0, 0, 0);
        }
    }

    // out_row = row0 + mi*16 + g*4 + reg ; out_col = col0 + ni*16 + c
    const int row0 = rowBase + wr * 64;
    const int col0 = colBase + wc * 64;

    float nbc[4];
#pragma unroll
    for (int ni = 0; ni < 4; ++ni) nbc[ni] = nb[col0 + ni * 16 + c];

    float colm2[4] = {BIGF, BIGF, BIGF, BIGF};
    f32x4 tot4 = (f32x4)0.f;
#pragma unroll
    for (int mi = 0; mi < 4; ++mi) {
        const f32x4 na4 = *(const f32x4*)(na + row0 + mi * 16 + g * 4);
        float rowm2[4] = {BIGF, BIGF, BIGF, BIGF};
#pragma unroll
        for (int ni = 0; ni < 4; ++ni) {
            f32x4 a = acc[mi][ni];
#pragma unroll
            for (int reg = 0; reg < 4; ++reg) {
                float d2 = fmaf(-2.0f, a[reg], na4[reg] + nbc[ni]);
                rowm2[reg] = fminf(rowm2[reg], d2);
                colm2[ni] = fminf(colm2[ni], d2);
                tot4[reg] += __builtin_amdgcn_sqrtf(fmaxf(d2, 0.f));
            }
        }
        // row d^2 mins: reduce across the 16 c-lanes
#pragma unroll
        for (int reg = 0; reg < 4; ++reg) {
            float m = rowm2[reg];
            m = fminf(m, __shfl_xor(m, 1, 64));
            m = fminf(m, __shfl_xor(m, 2, 64));
            m = fminf(m, __shfl_xor(m, 4, 64));
            m = fminf(m, __shfl_xor(m, 8, 64));
            if (c == 0) rmbuf[wc][wr * 64 + mi * 16 + g * 4 + reg] = m;
        }
    }
    // col d^2 mins: reduce across the 4 g-groups
#pragma unroll
    for (int ni = 0; ni < 4; ++ni) {
        float m = colm2[ni];
        m = fminf(m, __shfl_xor(m, 16, 64));
        m = fminf(m, __shfl_xor(m, 32, 64));
        if (g == 0) cmbuf[wr][wc * 64 + ni * 16 + c] = m;
    }
    // grand total: wave reduce
    float tot = (tot4[0] + tot4[1]) + (tot4[2] + tot4[3]);
#pragma unroll
    for (int off = 32; off >= 1; off >>= 1) tot += __shfl_xor(tot, off, 64);
    if (l == 0) tbuf[wid] = tot;
    __syncthreads();

    // plain disjoint stores - no atomics anywhere
    if (tid < 128) {
        rowpart[(size_t)bx * NN + rowBase + tid] = fminf(rmbuf[0][tid], rmbuf[1][tid]);
    } else if (tid < 256) {
        int j = tid - 128;
        colpart[(size_t)by * NN + colBase + j] = fminf(cmbuf[0][j], cmbuf[1][j]);
    }
    if (tid == 0)
        totpart[by * 64 + bx] = tbuf[0] + tbuf[1] + tbuf[2] + tbuf[3];
}

// ---------------- fin: 64-way partial reduce + last-block scalar emit ----------------
__global__ __launch_bounds__(256) void fin_kernel(const float* __restrict__ rowpart,
                                                  const float* __restrict__ colpart,
                                                  const float* __restrict__ totpart,
                                                  float* __restrict__ finpart,
                                                  unsigned int* __restrict__ done,
                                                  float* __restrict__ out) {
    const int idx = blockIdx.x * 256 + threadIdx.x;   // 0..16383
    const int j = (idx < NN) ? idx : idx - NN;
    const float* p = (idx < NN) ? rowpart : colpart;
    float m = BIGF;
#pragma unroll 8
    for (int k = 0; k < 64; ++k) m = fminf(m, p[(size_t)k * NN + j]);
    float contrib = -__builtin_amdgcn_sqrtf(fmaxf(m, 0.f)) * (1.0f / 16384.0f);
    if (blockIdx.x < 16)
        contrib += totpart[blockIdx.x * 256 + threadIdx.x] * (1.0f / 67108864.0f);
#pragma unroll
    for (int off = 32; off >= 1; off >>= 1) contrib += __shfl_xor(contrib, off, 64);
    __shared__ float red[4];
    __shared__ unsigned last;
    if ((threadIdx.x & 63) == 0) red[threadIdx.x >> 6] = contrib;
    __syncthreads();
    if (threadIdx.x == 0) {
        finpart[blockIdx.x] = red[0] + red[1] + red[2] + red[3];
        __threadfence();                       // release finpart
        last = (atomicAdd(done, 1u) == 63u) ? 1u : 0u;
    }
    __syncthreads();
    if (last && threadIdx.x < 64) {
        __threadfence();                       // acquire
        float s = __hip_atomic_load(&finpart[threadIdx.x], __ATOMIC_RELAXED,
                                    __HIP_MEMORY_SCOPE_AGENT);
#pragma unroll
        for (int off = 32; off >= 1; off >>= 1) s += __shfl_xor(s, off, 64);
        if (threadIdx.x == 0) out[0] = s + 1.0f - 1.0f / 8192.0f;
    }
}

extern "C" void kernel_launch(void* const* d_in, const int* in_sizes, int n_in,
                              void* d_out, int out_size, void* d_ws, size_t ws_size,
                              hipStream_t stream) {
    const float* A = (const float*)d_in[0];
    const float* B = (const float*)d_in[1];
    char* ws = (char*)d_ws;

    const size_t MB = 1024 * 1024;
    __hip_bfloat16* Abf = (__hip_bfloat16*)(ws);                  // 2 MB
    __hip_bfloat16* Bbf = (__hip_bfloat16*)(ws + 2 * MB);         // 2 MB
    float* na      = (float*)(ws + 4 * MB);                       // 32 KB
    float* nb      = (float*)(ws + 4 * MB + 32768);               // 32 KB
    float* rowpart = (float*)(ws + 4 * MB + 65536);               // 2 MB  [ct][8192]
    float* colpart = (float*)(ws + 6 * MB + 65536);               // 2 MB  [rt][8192]
    float* totpart = (float*)(ws + 8 * MB + 65536);               // 16 KB
    float* finpart = (float*)(ws + 8 * MB + 65536 + 16384);       // 256 B
    unsigned int* done = (unsigned int*)(ws + 8 * MB + 65536 + 16384 + 256);

    dim3 pgrid(NN / 8, 2);
    prep_kernel<<<pgrid, 256, 0, stream>>>(A, B, Abf, Bbf, na, nb, done);

    dim3 grid(NN / 128, NN / 128);
    dist_fused<<<grid, 256, 0, stream>>>(Abf, Bbf, na, nb, rowpart, colpart, totpart);

    fin_kernel<<<64, 256, 0, stream>>>(rowpart, colpart, totpart, finpart, done,
                                       (float*)d_out);
}